// Round 4
// baseline (61.490 us; speedup 1.0000x reference)
//
#include <hip/hip_runtime.h>

// Problem constants (fixed by reference setup_inputs)
#define BN 512
#define CCH 32
#define TT 4096
#define SEG 4   // waves (segments) per row; each wave does K/SEG bins

// Pad LDS by +4 floats per 32: float4 staging writes keep 16B alignment
// (4-aligned idx -> 4-aligned padded idx), bin reads spread across banks.
__device__ __forceinline__ int padidx(int i) { return i + ((i >> 5) << 2); }

// Max staged slice: te-a0 <= L/SEG + 1 + 3 <= 1028 floats.
// padidx(1027) = 1027 + 128 = 1155 -> allocate 1160.
#define SLDS 1160

__global__ __launch_bounds__(64) void pool_waveseg(
    const float* __restrict__ f, const float* __restrict__ m,
    const int* __restrict__ vlen,
    float* __restrict__ out_f, float* __restrict__ out_m, int K)
{
    __shared__ float sf[SLDS];
    __shared__ float sm[SLDS];

    const int wid  = blockIdx.x;
    const int seg  = wid & (SEG - 1);
    const int bc   = wid >> 2;          // log2(SEG) = 2
    const int b    = bc / CCH;
    const int lane = threadIdx.x;

    // valid_lengths may be int64 (JAX x64 on) or int32 (x64 off).
    // int64 LE: all high words are 0 since values < 4096.
    bool is64 = ((vlen[1] | vlen[3] | vlen[5] | vlen[7] |
                  vlen[9] | vlen[11] | vlen[13] | vlen[15]) == 0);
    int len = is64 ? vlen[2 * b] : vlen[b];

    int L   = len < 1 ? 1 : (len > TT ? TT : len);
    int off = TT - L;

    int BK = (K + SEG - 1) / SEG;       // bins per segment (64 for K=256)
    int k0 = seg * BK;
    int k1 = k0 + BK; if (k1 > K) k1 = K;
    if (k0 >= K) return;

    unsigned uL = (unsigned)L, uK = (unsigned)K;

    // Segment's t-range: [ts, te)
    int ts = off + (int)((uL * (unsigned)k0) / uK);
    int te = off + (int)((uL * (unsigned)k1 + uK - 1u) / uK);
    if (te > TT) te = TT;
    int a0 = ts & ~3;                   // 16B-aligned staging start
    int nv = (te - a0 + 3) >> 2;        // float4 count; a0+4*nv <= TT
                                        // (a0,TT mult of 4, te<=TT)

    const float* fr = f + (size_t)bc * TT;
    const float* mr = m + (size_t)bc * TT;

    // Stage slice [a0, a0+4*nv) of both rows into LDS, coalesced float4.
    for (int i = lane; i < nv; i += 64) {
        int t0 = a0 + (i << 2);
        float4 vf = *(const float4*)(fr + t0);
        float4 vm = *(const float4*)(mr + t0);
        int p = padidx(i << 2);         // relative, 4-aligned
        *(float4*)&sf[p] = vf;
        *(float4*)&sm[p] = vm;
    }
    __syncthreads();

    // One bin per lane (loop only if BK > 64).
    for (int k = k0 + lane; k < k1; k += 64) {
        int si = off + (int)((uL * (unsigned)k) / uK);
        int ei = off + (int)((uL * (unsigned)(k + 1) + uK - 1u) / uK);
        if (ei > TT) ei = TT;
        int count = ei - si;
        if (count < 1) count = 1;

        float af = 0.0f, am = 0.0f;
        for (int t = si; t < ei; ++t) {
            int p = padidx(t - a0);
            af += sf[p];
            am += sm[p];
        }
        float inv = 1.0f / (float)count;
        size_t o = (size_t)bc * K + k;
        out_f[o] = af * inv;
        out_m[o] = am * inv;
    }
}

extern "C" void kernel_launch(void* const* d_in, const int* in_sizes, int n_in,
                              void* d_out, int out_size, void* d_ws, size_t ws_size,
                              hipStream_t stream) {
    const float* f    = (const float*)d_in[0];
    const float* m    = (const float*)d_in[1];
    const int*   vlen = (const int*)d_in[2];

    // K derived from output size: out = 2 * BN * C * K floats
    int K = out_size / (2 * BN * CCH);
    if (K < 1) K = 1;

    float* out_f = (float*)d_out;
    float* out_m = out_f + (size_t)BN * CCH * K;

    int grid = BN * CCH * SEG;   // 65536 single-wave blocks
    pool_waveseg<<<grid, 64, 0, stream>>>(f, m, vlen, out_f, out_m, K);
}